// Round 14
// baseline (5326.634 us; speedup 1.0000x reference)
//
#include <hip/hip_runtime.h>
#include <math.h>

#define T_SEQ 512
#define BATCH 256
#define HID   512
#define IN0   64
#define K1    1024           /* L1: 512 h0 + 512 h1 */
#define K0    576            /* L0: 64 x + 512 h0   */
#define NWG   256
#define NTHR  256
#define LDS_DYN 133632       /* 128 KB weights + 4 x 640 B transpose buffers */

typedef _Float16 f16x8 __attribute__((ext_vector_type(8)));
typedef float    f32x4 __attribute__((ext_vector_type(4)));

__device__ __forceinline__ float sigm(float x)   { return 1.0f / (1.0f + __expf(-x)); }
__device__ __forceinline__ float tanh_f(float x) { return 2.0f / (1.0f + __expf(-2.0f * x)) - 1.0f; }

__device__ __forceinline__ f32x4 mfma16(f16x8 a, f16x8 b, f32x4 c) {
  return __builtin_amdgcn_mfma_f32_16x16x32_f16(a, b, c, 0, 0, 0);
}

// write-through stores to the coherence point (no dirty L2 anywhere)
__device__ __forceinline__ void store_dwordx2_wt(const _Float16* p, unsigned long long v) {
  asm volatile("global_store_dwordx2 %0, %1, off sc0 sc1"
               :: "v"((const void*)p), "v"(v) : "memory");
}
__device__ __forceinline__ void store_dword_wt(const unsigned* p, unsigned v) {
  asm volatile("global_store_dword %0, %1, off sc0 sc1"
               :: "v"((const void*)p), "v"(v) : "memory");
}

// ---------- prep: W -> fp16, rows permuted r = hcol*4 + gate, k-concat ih|hh ----------
// out layout: [slice s=r>>4][kc=k>>3][row16=r&15][ke=k&7]  (16-B chunks contiguous)
__global__ void k_split_w(const float* __restrict__ Wih, const float* __restrict__ Whh,
                          const float* __restrict__ bih, const float* __restrict__ bhh,
                          _Float16* __restrict__ whi, float* __restrict__ bias, int Kin) {
  int K = Kin + HID;
  long idx = (long)blockIdx.x * 256 + threadIdx.x;
  long total = 2048L * K;
  if (idx < total) {
    int k = (int)(idx % K);
    int r = (int)(idx / K);
    int gate = r & 3, hcol = r >> 2;
    int row = gate * HID + hcol;
    float v = (k < Kin) ? Wih[(long)row * Kin + k] : Whh[(long)row * HID + (k - Kin)];
    long o = (long)(r >> 4) * 16 * K + (long)(k >> 3) * 128 + (r & 15) * 8 + (k & 7);
    whi[o] = (_Float16)v;
  }
  if (idx < 2048) {
    int r = (int)idx;
    int gate = r & 3, hcol = r >> 2;
    int row = gate * HID + hcol;
    bias[r] = bih[row] + bhh[row];
  }
}

// ---------- prep: x[B][T][I] -> fp16 [T][B][I] ----------
__global__ void k_split_x(const float* __restrict__ x, _Float16* __restrict__ x16) {
  int idx = blockIdx.x * 256 + threadIdx.x;   // dst index, [t][b][i]
  int i = idx & 63;
  int b = (idx >> 6) & 255;
  int t = idx >> 14;
  x16[idx] = (_Float16)x[((size_t)b * T_SEQ + t) * IN0 + i];
}

// ---------- two-level tree grid barrier + mirrored release lines (r12-proven) ----------
// bar[0]          : top counter; epoch e complete when top hits 8*e
// bar[32+g*32]    : per-group arrival counter (g = wg&7, 32 members each)
// bar[512+g*32]   : per-group release mirror (polled line, one per group)
// All counters monotonic -> no reset race. Data release ordering comes from
// callers' s_waitcnt vmcnt(0) after write-through stores; acquire fence
// (buffer_inv only) makes peers' WT stores visible after release.
__device__ __forceinline__ void grid_barrier(unsigned* bar, unsigned epoch) {
  __syncthreads();
  if (threadIdx.x == 0) {
    const unsigned g = blockIdx.x & 7;
    unsigned a = __hip_atomic_fetch_add(&bar[32 + g * 32], 1u,
                                        __ATOMIC_RELAXED, __HIP_MEMORY_SCOPE_AGENT);
    if (a == epoch * 32u - 1u) {   // 32nd arrival of this epoch in this group
      unsigned t = __hip_atomic_fetch_add(&bar[0], 1u,
                                          __ATOMIC_RELAXED, __HIP_MEMORY_SCOPE_AGENT);
      if (t == epoch * 8u - 1u) {  // last group in: broadcast release
        #pragma unroll
        for (int gg = 0; gg < 8; ++gg)
          store_dword_wt(&bar[512 + gg * 32], epoch);
      }
    }
    while ((int)(__hip_atomic_load(&bar[512 + g * 32],
                                   __ATOMIC_RELAXED, __HIP_MEMORY_SCOPE_AGENT) - epoch) < 0)
      __builtin_amdgcn_s_sleep(4);
    __builtin_amdgcn_fence(__ATOMIC_ACQUIRE, "agent");   // buffer_inv only
  }
  __syncthreads();
}

// ---------- persistent MFMA LSTM (fp16, 64-row tiles, transpose-store) ----------
// 256 wgs x 256 thr (4 waves, 1/SIMD). wg<128: layer1, rg=(wg&127)>>2, bg=wg&3;
// wg>=128: layer0 same on (wg-128). wg tile = 64 rows x 64 batch.
// Wave wv: batch block bg*64+wv*16 (EXCLUSIVE 16-col B tile -> B issued once per
// byte per CU); computes all 4 row-slices: acc[4], c[4].
// fp16 weights for the wg's 64 rows in 128 KB dynamic LDS, loaded ONCE.
// h-store: wave's 16x16 (batch x col) tile is transposed via a padded per-wave
// LDS buffer [16][20] so each lane issues ONE contiguous 8-B WT store
// (64 stores/wave vs 256 scattered 2-B stores -> kills the 4x write RMW).
// D layout: col=lane&15 (batch), row=(lane>>4)*4+reg. Rows permuted hcol*4+gate =>
// lane's 4 acc regs = i,f,g,o of one (hcol,batch): cell update lane-local, c in regs.
// Activations in1 (fp16) [2][256][1024]: cols 0..511 = h0, 512..1023 = h1, k-major.
__global__ __launch_bounds__(NTHR, 1) void k_lstm(
    const _Float16* __restrict__ x16,
    const _Float16* __restrict__ w0, const float* __restrict__ bias0,
    const _Float16* __restrict__ w1, const float* __restrict__ bias1,
    _Float16* __restrict__ in1,
    const float* __restrict__ fcw, const float* __restrict__ fcb,
    float* __restrict__ out, unsigned* __restrict__ bar)
{
  extern __shared__ __align__(16) _Float16 ldsA[];   // [64 x KW weights | 4 x [16][20] tbuf]

  const int tid  = threadIdx.x;
  const int lane = tid & 63;
  const int wv   = __builtin_amdgcn_readfirstlane(tid >> 6);   // 0..3
  const int wg   = blockIdx.x;
  const int layer1 = (wg < 128) ? 1 : 0;
  const int lw   = wg & 127;
  const int rg   = lw >> 2;            // 0..31 row-group (64 rows)
  const int bg   = lw & 3;             // 0..3 batch-group (64 batch)
  const int bbase = bg * 64 + wv * 16;
  const int lr = lane & 15;            // A-row16 / B-batch / D-col offset
  const int lg = lane >> 4;            // k-subgroup (A/B), row-subgroup (D)
  const int KW = layer1 ? K1 : K0;

  // ---- one-time: load this wg's 64-row weight slice into LDS ----
  {
    const f16x8* gw = reinterpret_cast<const f16x8*>((layer1 ? w1 : w0) + (size_t)rg * 64 * KW);
    f16x8* lw16 = reinterpret_cast<f16x8*>(ldsA);
    const int nch = 8 * KW;            // 64*KW/8 chunks of 16 B
    for (int ch = tid; ch < nch; ch += NTHR) lw16[ch] = gw[ch];
  }
  __syncthreads();

  // lane's hidden columns (4 row-slices) and biases
  const float* bsrc = layer1 ? bias1 : bias0;
  float4 b4[4];
  #pragma unroll
  for (int sl = 0; sl < 4; ++sl)
    b4[sl] = *reinterpret_cast<const float4*>(bsrc + (rg * 16 + sl * 4 + lg) * 4);
  const f16x8* A = reinterpret_cast<const f16x8*>(ldsA);   // slice sl at sl*2*KW (f16x8 units)
  _Float16* tbuf = ldsA + 64 * K1 + wv * 320;              // per-wave [16][20] transpose buffer

  // store geometry (after transpose): lane -> (batch row, 4-col chunk)
  const int colgrp = (layer1 ? 512 : 0) + rg * 16;
  const int srow = lane >> 2;          // 0..15 batch row
  const int scq  = lane & 3;           // 0..3 col quad

  float c[4] = {0.f, 0.f, 0.f, 0.f};

  #pragma unroll 1
  for (int n = 0; n <= T_SEQ; ++n) {
    const int pr = (n + 1) & 1;   // read parity
    const int pw = n & 1;         // write parity
    const bool active = layer1 ? (n >= 1) : (n < T_SEQ);
    if (active) {
      f32x4 acc[4];
      #pragma unroll
      for (int sl = 0; sl < 4; ++sl) {
        acc[sl][0]=b4[sl].x; acc[sl][1]=b4[sl].y; acc[sl][2]=b4[sl].z; acc[sl][3]=b4[sl].w;
      }

      const _Float16* Bp = in1 + ((size_t)pr * BATCH + bbase) * K1 + (size_t)lr * K1 + lg * 8;

      if (layer1) {
        // 32 k-chunks; loads issued ahead, compiler schedules waits
        f16x8 bufA[16], bufB[16];
        #pragma unroll
        for (int kk = 0; kk < 16; ++kk)
          bufA[kk] = *reinterpret_cast<const f16x8*>(Bp + (size_t)kk * 32);
        #pragma unroll
        for (int kk = 0; kk < 16; ++kk)
          bufB[kk] = *reinterpret_cast<const f16x8*>(Bp + (size_t)(16 + kk) * 32);
        #pragma unroll
        for (int kk = 0; kk < 16; ++kk) {
          const int ac = (kk * 4 + lg) * 16 + lr;
          #pragma unroll
          for (int sl = 0; sl < 4; ++sl)
            acc[sl] = mfma16(A[(size_t)sl * 2 * K1 + ac], bufA[kk], acc[sl]);
        }
        #pragma unroll
        for (int kk = 0; kk < 16; ++kk) {
          const int ac = ((16 + kk) * 4 + lg) * 16 + lr;
          #pragma unroll
          for (int sl = 0; sl < 4; ++sl)
            acc[sl] = mfma16(A[(size_t)sl * 2 * K1 + ac], bufB[kk], acc[sl]);
        }
      } else {
        // x part (2 k-chunks) + h0 part (16 k-chunks)
        const _Float16* Xp = x16 + ((size_t)n * BATCH + bbase) * IN0 + (size_t)lr * IN0 + lg * 8;
        f16x8 xb[2];
        xb[0] = *reinterpret_cast<const f16x8*>(Xp);
        xb[1] = *reinterpret_cast<const f16x8*>(Xp + 32);
        f16x8 bufA[16];
        #pragma unroll
        for (int kk = 0; kk < 16; ++kk)
          bufA[kk] = *reinterpret_cast<const f16x8*>(Bp + (size_t)kk * 32);
        #pragma unroll
        for (int ks = 0; ks < 2; ++ks) {
          const int ac = (ks * 4 + lg) * 16 + lr;
          #pragma unroll
          for (int sl = 0; sl < 4; ++sl)
            acc[sl] = mfma16(A[(size_t)sl * 2 * K0 + ac], xb[ks], acc[sl]);
        }
        #pragma unroll
        for (int kk = 0; kk < 16; ++kk) {
          const int ac = (8 + kk * 4 + lg) * 16 + lr;   // weight k-offset 64
          #pragma unroll
          for (int sl = 0; sl < 4; ++sl)
            acc[sl] = mfma16(A[(size_t)sl * 2 * K0 + ac], bufA[kk], acc[sl]);
        }
      }

      // ---- lane-local cell update; transpose via LDS; contiguous WT store ----
      #pragma unroll
      for (int sl = 0; sl < 4; ++sl) {
        float i_ = sigm(acc[sl][0]);
        float f_ = sigm(acc[sl][1]);
        float g_ = tanh_f(acc[sl][2]);
        float o_ = sigm(acc[sl][3]);
        c[sl] = fmaf(f_, c[sl], i_ * g_);
        float hv = o_ * tanh_f(c[sl]);
        tbuf[lr * 20 + sl * 4 + lg] = (_Float16)hv;   // [batch lr][col cc]
      }
      asm volatile("s_waitcnt lgkmcnt(0)" ::: "memory");   // wave-local LDS visibility
      {
        unsigned long long v =
            *reinterpret_cast<const unsigned long long*>(tbuf + srow * 20 + scq * 4);
        const _Float16* gp = in1 + ((size_t)pw * BATCH + bbase + srow) * K1 + colgrp + scq * 4;
        store_dwordx2_wt(gp, v);
      }
      asm volatile("s_waitcnt vmcnt(0)" ::: "memory");  // release: stores at coherence point
    }
    grid_barrier(bar, (unsigned)(n + 1));
  }

  // ---- final FC on h1[511] (written at iter 512, parity 0), cols 512..1023 ----
  if (wg == 0 && tid < BATCH) {
    const _Float16* r = in1 + (size_t)tid * K1 + 512;
    float acc = 0.f;
    #pragma unroll 8
    for (int k = 0; k < HID; ++k)
      acc = fmaf((float)r[k], fcw[k], acc);
    out[tid] = acc + fcb[0];
  }
}

// ---------- host ----------
extern "C" void kernel_launch(void* const* d_in, const int* in_sizes, int n_in,
                              void* d_out, int out_size, void* d_ws, size_t ws_size,
                              hipStream_t stream) {
  const float* x    = (const float*)d_in[0];
  const float* Wih0 = (const float*)d_in[1];
  const float* Whh0 = (const float*)d_in[2];
  const float* bih0 = (const float*)d_in[3];
  const float* bhh0 = (const float*)d_in[4];
  const float* Wih1 = (const float*)d_in[5];
  const float* Whh1 = (const float*)d_in[6];
  const float* bih1 = (const float*)d_in[7];
  const float* bhh1 = (const float*)d_in[8];
  const float* fcw  = (const float*)d_in[9];
  const float* fcb  = (const float*)d_in[10];

  char* ws = (char*)d_ws;
  size_t off = 0;
  auto alloc = [&](size_t bytes) -> char* {
    char* pp = ws + off;
    off = (off + bytes + 1023) & ~(size_t)1023;
    return pp;
  };
  unsigned*  bar  = (unsigned*)alloc(4096);
  _Float16* x16  = (_Float16*)alloc((size_t)T_SEQ * BATCH * IN0 * 2);   // 16.8 MB
  _Float16* w0   = (_Float16*)alloc((size_t)2048 * K0 * 2);             // 2.36 MB
  _Float16* w1   = (_Float16*)alloc((size_t)2048 * K1 * 2);             // 4.2 MB
  float*    bias0 = (float*)alloc(2048 * 4);
  float*    bias1 = (float*)alloc(2048 * 4);
  _Float16* in1  = (_Float16*)alloc((size_t)2 * BATCH * K1 * 2);        // 1 MB

  (void)hipFuncSetAttribute(reinterpret_cast<const void*>(k_lstm),
                            hipFuncAttributeMaxDynamicSharedMemorySize, LDS_DYN);

  (void)hipMemsetAsync(bar, 0, 4096, stream);
  (void)hipMemsetAsync(in1, 0, (size_t)2 * BATCH * K1 * 2, stream);
  k_split_x<<<(T_SEQ * BATCH * IN0) / 256, 256, 0, stream>>>(x, x16);
  k_split_w<<<(int)((2048L * K0 + 255) / 256), 256, 0, stream>>>(Wih0, Whh0, bih0, bhh0, w0, bias0, IN0);
  k_split_w<<<(int)((2048L * K1 + 255) / 256), 256, 0, stream>>>(Wih1, Whh1, bih1, bhh1, w1, bias1, HID);
  k_lstm<<<NWG, NTHR, LDS_DYN, stream>>>(x16, w0, bias0, w1, bias1,
                                         in1, fcw, fcb, (float*)d_out, bar);
}

// Round 15
// 4554.204 us; speedup vs baseline: 1.1696x; 1.1696x over previous
//
#include <hip/hip_runtime.h>
#include <math.h>

#define T_SEQ 512
#define BATCH 256
#define HID   512
#define IN0   64
#define K1    1024           /* L1: 512 h0 + 512 h1 */
#define K0    576            /* L0: 64 x + 512 h0   */
#define NWG   256
#define NTHR  256
#define LDS_DYN 131072

typedef _Float16 f16x8 __attribute__((ext_vector_type(8)));
typedef float    f32x4 __attribute__((ext_vector_type(4)));

__device__ __forceinline__ float sigm(float x)   { return 1.0f / (1.0f + __expf(-x)); }
__device__ __forceinline__ float tanh_f(float x) { return 2.0f / (1.0f + __expf(-2.0f * x)) - 1.0f; }

__device__ __forceinline__ f32x4 mfma16(f16x8 a, f16x8 b, f32x4 c) {
  return __builtin_amdgcn_mfma_f32_16x16x32_f16(a, b, c, 0, 0, 0);
}

// ---- coherence-point (IF$) bypass ops: nothing is ever cached stale ----
__device__ __forceinline__ f16x8 load_f16x8_cc(const _Float16* p) {
  f16x8 r;
  asm volatile("global_load_dwordx4 %0, %1, off sc0 sc1"
               : "=v"(r) : "v"((const void*)p));
  return r;
}
__device__ __forceinline__ void store_short_wt(const _Float16* p, unsigned v) {
  asm volatile("global_store_short %0, %1, off sc0 sc1"
               :: "v"((const void*)p), "v"(v) : "memory");
}
__device__ __forceinline__ void store_dword_wt(const unsigned* p, unsigned v) {
  asm volatile("global_store_dword %0, %1, off sc0 sc1"
               :: "v"((const void*)p), "v"(v) : "memory");
}

// ---------- prep: W -> fp16, rows permuted r = hcol*4 + gate, k-concat ih|hh ----------
// out layout: [slice s=r>>4][kc=k>>3][row16=r&15][ke=k&7]  (16-B chunks contiguous)
__global__ void k_split_w(const float* __restrict__ Wih, const float* __restrict__ Whh,
                          const float* __restrict__ bih, const float* __restrict__ bhh,
                          _Float16* __restrict__ whi, float* __restrict__ bias, int Kin) {
  int K = Kin + HID;
  long idx = (long)blockIdx.x * 256 + threadIdx.x;
  long total = 2048L * K;
  if (idx < total) {
    int k = (int)(idx % K);
    int r = (int)(idx / K);
    int gate = r & 3, hcol = r >> 2;
    int row = gate * HID + hcol;
    float v = (k < Kin) ? Wih[(long)row * Kin + k] : Whh[(long)row * HID + (k - Kin)];
    long o = (long)(r >> 4) * 16 * K + (long)(k >> 3) * 128 + (r & 15) * 8 + (k & 7);
    whi[o] = (_Float16)v;
  }
  if (idx < 2048) {
    int r = (int)idx;
    int gate = r & 3, hcol = r >> 2;
    int row = gate * HID + hcol;
    bias[r] = bih[row] + bhh[row];
  }
}

// ---------- prep: x[B][T][I] -> fp16 [T][B][I] ----------
__global__ void k_split_x(const float* __restrict__ x, _Float16* __restrict__ x16) {
  int idx = blockIdx.x * 256 + threadIdx.x;   // dst index, [t][b][i]
  int i = idx & 63;
  int b = (idx >> 6) & 255;
  int t = idx >> 14;
  x16[idx] = (_Float16)x[((size_t)b * T_SEQ + t) * IN0 + i];
}

// ---------- two-level tree grid barrier, NO acquire fence ----------
// bar[0]          : top counter; epoch e complete when top hits 8*e
// bar[32+g*32]    : per-group arrival counter (g = wg&7, 32 members each)
// bar[512+g*32]   : per-group release mirror (polled line, one per group)
// All counters monotonic -> no reset race. Data release: callers drain WT
// stores (s_waitcnt vmcnt(0)) before arriving. Data acquire: ALL cross-wg
// data (in1) is read via sc0sc1 bypass loads -> no stale copy can exist in
// any L1/L2, so no per-iteration buffer_inv is needed.
__device__ __forceinline__ void grid_barrier(unsigned* bar, unsigned epoch) {
  __syncthreads();
  if (threadIdx.x == 0) {
    const unsigned g = blockIdx.x & 7;
    unsigned a = __hip_atomic_fetch_add(&bar[32 + g * 32], 1u,
                                        __ATOMIC_RELAXED, __HIP_MEMORY_SCOPE_AGENT);
    if (a == epoch * 32u - 1u) {   // 32nd arrival of this epoch in this group
      unsigned t = __hip_atomic_fetch_add(&bar[0], 1u,
                                          __ATOMIC_RELAXED, __HIP_MEMORY_SCOPE_AGENT);
      if (t == epoch * 8u - 1u) {  // last group in: broadcast release
        #pragma unroll
        for (int gg = 0; gg < 8; ++gg)
          store_dword_wt(&bar[512 + gg * 32], epoch);
      }
    }
    while ((int)(__hip_atomic_load(&bar[512 + g * 32],
                                   __ATOMIC_RELAXED, __HIP_MEMORY_SCOPE_AGENT) - epoch) < 0)
      __builtin_amdgcn_s_sleep(4);
  }
  __syncthreads();
}

// ---------- persistent MFMA LSTM (fp16, 64-row tiles, fence-free loop) ----------
// 256 wgs x 256 thr (4 waves, 1/SIMD). wg<128: layer1, rg=(wg&127)>>2, bg=wg&3;
// wg>=128: layer0 same on (wg-128). wg tile = 64 rows x 64 batch.
// Wave wv: batch block bg*64+wv*16 (EXCLUSIVE 16-col B tile -> B issued once per
// byte per CU); computes all 4 row-slices: acc[4], c[4].
// fp16 weights for the wg's 64 rows in 128 KB dynamic LDS, loaded ONCE.
// Inner-loop h/x loads are sc0sc1 bypass (asm) with counted vmcnt waits
// (vmcnt(16) -> first half, vmcnt(0) -> rest) + sched_barrier(0) after each
// wait (asm loads are invisible to compiler vmcnt tracking — rule #18).
// D layout: col=lane&15 (batch), row=(lane>>4)*4+reg. Rows permuted hcol*4+gate =>
// lane's 4 acc regs = i,f,g,o of one (hcol,batch): cell update lane-local, c in regs.
// Activations in1 (fp16) [2][256][1024]: cols 0..511 = h0, 512..1023 = h1, k-major.
__global__ __launch_bounds__(NTHR, 1) void k_lstm(
    const _Float16* __restrict__ x16,
    const _Float16* __restrict__ w0, const float* __restrict__ bias0,
    const _Float16* __restrict__ w1, const float* __restrict__ bias1,
    _Float16* __restrict__ in1,
    const float* __restrict__ fcw, const float* __restrict__ fcb,
    float* __restrict__ out, unsigned* __restrict__ bar)
{
  extern __shared__ __align__(16) _Float16 ldsA[];   // 64 rows x KW fp16

  const int tid  = threadIdx.x;
  const int lane = tid & 63;
  const int wv   = __builtin_amdgcn_readfirstlane(tid >> 6);   // 0..3
  const int wg   = blockIdx.x;
  const int layer1 = (wg < 128) ? 1 : 0;
  const int lw   = wg & 127;
  const int rg   = lw >> 2;            // 0..31 row-group (64 rows)
  const int bg   = lw & 3;             // 0..3 batch-group (64 batch)
  const int bbase = bg * 64 + wv * 16;
  const int lr = lane & 15;            // A-row16 / B-batch / D-col offset
  const int lg = lane >> 4;            // k-subgroup (A/B), row-subgroup (D)
  const int KW = layer1 ? K1 : K0;

  // ---- one-time: load this wg's 64-row weight slice into LDS ----
  {
    const f16x8* gw = reinterpret_cast<const f16x8*>((layer1 ? w1 : w0) + (size_t)rg * 64 * KW);
    f16x8* lw16 = reinterpret_cast<f16x8*>(ldsA);
    const int nch = 8 * KW;            // 64*KW/8 chunks of 16 B
    for (int ch = tid; ch < nch; ch += NTHR) lw16[ch] = gw[ch];
  }
  __syncthreads();

  // lane's hidden columns (4 row-slices) and biases
  const float* bsrc = layer1 ? bias1 : bias0;
  float4 b4[4];
  int hcv[4];
  #pragma unroll
  for (int sl = 0; sl < 4; ++sl) {
    hcv[sl] = rg * 16 + sl * 4 + lg;
    b4[sl] = *reinterpret_cast<const float4*>(bsrc + hcv[sl] * 4);
  }
  const f16x8* A = reinterpret_cast<const f16x8*>(ldsA);   // slice sl at sl*2*KW (f16x8 units)

  float c[4] = {0.f, 0.f, 0.f, 0.f};

  #pragma unroll 1
  for (int n = 0; n <= T_SEQ; ++n) {
    const int pr = (n + 1) & 1;   // read parity
    const int pw = n & 1;         // write parity
    const bool active = layer1 ? (n >= 1) : (n < T_SEQ);
    if (active) {
      f32x4 acc[4];
      #pragma unroll
      for (int sl = 0; sl < 4; ++sl) {
        acc[sl][0]=b4[sl].x; acc[sl][1]=b4[sl].y; acc[sl][2]=b4[sl].z; acc[sl][3]=b4[sl].w;
      }

      const _Float16* Bp = in1 + ((size_t)pr * BATCH + bbase) * K1 + (size_t)lr * K1 + lg * 8;

      if (layer1) {
        // 32 k-chunks, all loads issued as sc-bypass; counted waits split halves
        f16x8 bufA[16], bufB[16];
        #pragma unroll
        for (int kk = 0; kk < 16; ++kk)
          bufA[kk] = load_f16x8_cc(Bp + (size_t)kk * 32);
        #pragma unroll
        for (int kk = 0; kk < 16; ++kk)
          bufB[kk] = load_f16x8_cc(Bp + (size_t)(16 + kk) * 32);
        asm volatile("s_waitcnt vmcnt(16)" ::: "memory");   // bufA complete
        __builtin_amdgcn_sched_barrier(0);
        #pragma unroll
        for (int kk = 0; kk < 16; ++kk) {
          const int ac = (kk * 4 + lg) * 16 + lr;
          #pragma unroll
          for (int sl = 0; sl < 4; ++sl)
            acc[sl] = mfma16(A[(size_t)sl * 2 * K1 + ac], bufA[kk], acc[sl]);
        }
        asm volatile("s_waitcnt vmcnt(0)" ::: "memory");    // bufB complete
        __builtin_amdgcn_sched_barrier(0);
        #pragma unroll
        for (int kk = 0; kk < 16; ++kk) {
          const int ac = ((16 + kk) * 4 + lg) * 16 + lr;
          #pragma unroll
          for (int sl = 0; sl < 4; ++sl)
            acc[sl] = mfma16(A[(size_t)sl * 2 * K1 + ac], bufB[kk], acc[sl]);
        }
      } else {
        // x part (2 chunks) + h0 part (16 chunks); x loads are oldest -> return first
        const _Float16* Xp = x16 + ((size_t)n * BATCH + bbase) * IN0 + (size_t)lr * IN0 + lg * 8;
        f16x8 xb0 = load_f16x8_cc(Xp);
        f16x8 xb1 = load_f16x8_cc(Xp + 32);
        f16x8 bufA[16];
        #pragma unroll
        for (int kk = 0; kk < 16; ++kk)
          bufA[kk] = load_f16x8_cc(Bp + (size_t)kk * 32);
        asm volatile("s_waitcnt vmcnt(16)" ::: "memory");   // xb0, xb1 complete
        __builtin_amdgcn_sched_barrier(0);
        #pragma unroll
        for (int sl = 0; sl < 4; ++sl)
          acc[sl] = mfma16(A[(size_t)sl * 2 * K0 + (lg * 16 + lr)], xb0, acc[sl]);
        #pragma unroll
        for (int sl = 0; sl < 4; ++sl)
          acc[sl] = mfma16(A[(size_t)sl * 2 * K0 + ((4 + lg) * 16 + lr)], xb1, acc[sl]);
        asm volatile("s_waitcnt vmcnt(0)" ::: "memory");    // bufA complete
        __builtin_amdgcn_sched_barrier(0);
        #pragma unroll
        for (int kk = 0; kk < 16; ++kk) {
          const int ac = (8 + kk * 4 + lg) * 16 + lr;   // weight k-offset 64
          #pragma unroll
          for (int sl = 0; sl < 4; ++sl)
            acc[sl] = mfma16(A[(size_t)sl * 2 * K0 + ac], bufA[kk], acc[sl]);
        }
      }

      // ---- lane-local cell update; write-through fp16 h stores ----
      const int b = bbase + lr;
      #pragma unroll
      for (int sl = 0; sl < 4; ++sl) {
        float i_ = sigm(acc[sl][0]);
        float f_ = sigm(acc[sl][1]);
        float g_ = tanh_f(acc[sl][2]);
        float o_ = sigm(acc[sl][3]);
        c[sl] = fmaf(f_, c[sl], i_ * g_);
        float hv = o_ * tanh_f(c[sl]);
        _Float16 h16 = (_Float16)hv;
        const int col = (layer1 ? 512 : 0) + hcv[sl];
        const size_t idx = ((size_t)pw * BATCH + b) * K1 + col;
        store_short_wt(in1 + idx, (unsigned)__builtin_bit_cast(unsigned short, h16));
      }
      asm volatile("s_waitcnt vmcnt(0)" ::: "memory");  // release: stores at coherence point
    }
    grid_barrier(bar, (unsigned)(n + 1));
  }

  // ---- final FC on h1[511] (written at iter 512, parity 0), cols 512..1023 ----
  if (wg == 0 && tid < BATCH) {
    __builtin_amdgcn_fence(__ATOMIC_ACQUIRE, "agent");   // one-time acquire
    const _Float16* r = in1 + (size_t)tid * K1 + 512;
    float acc = 0.f;
    #pragma unroll 8
    for (int k = 0; k < HID; ++k)
      acc = fmaf((float)r[k], fcw[k], acc);
    out[tid] = acc + fcb[0];
  }
}

// ---------- host ----------
extern "C" void kernel_launch(void* const* d_in, const int* in_sizes, int n_in,
                              void* d_out, int out_size, void* d_ws, size_t ws_size,
                              hipStream_t stream) {
  const float* x    = (const float*)d_in[0];
  const float* Wih0 = (const float*)d_in[1];
  const float* Whh0 = (const float*)d_in[2];
  const float* bih0 = (const float*)d_in[3];
  const float* bhh0 = (const float*)d_in[4];
  const float* Wih1 = (const float*)d_in[5];
  const float* Whh1 = (const float*)d_in[6];
  const float* bih1 = (const float*)d_in[7];
  const float* bhh1 = (const float*)d_in[8];
  const float* fcw  = (const float*)d_in[9];
  const float* fcb  = (const float*)d_in[10];

  char* ws = (char*)d_ws;
  size_t off = 0;
  auto alloc = [&](size_t bytes) -> char* {
    char* pp = ws + off;
    off = (off + bytes + 1023) & ~(size_t)1023;
    return pp;
  };
  unsigned*  bar  = (unsigned*)alloc(4096);
  _Float16* x16  = (_Float16*)alloc((size_t)T_SEQ * BATCH * IN0 * 2);   // 16.8 MB
  _Float16* w0   = (_Float16*)alloc((size_t)2048 * K0 * 2);             // 2.36 MB
  _Float16* w1   = (_Float16*)alloc((size_t)2048 * K1 * 2);             // 4.2 MB
  float*    bias0 = (float*)alloc(2048 * 4);
  float*    bias1 = (float*)alloc(2048 * 4);
  _Float16* in1  = (_Float16*)alloc((size_t)2 * BATCH * K1 * 2);        // 1 MB

  (void)hipFuncSetAttribute(reinterpret_cast<const void*>(k_lstm),
                            hipFuncAttributeMaxDynamicSharedMemorySize, LDS_DYN);

  (void)hipMemsetAsync(bar, 0, 4096, stream);
  (void)hipMemsetAsync(in1, 0, (size_t)2 * BATCH * K1 * 2, stream);
  k_split_x<<<(T_SEQ * BATCH * IN0) / 256, 256, 0, stream>>>(x, x16);
  k_split_w<<<(int)((2048L * K0 + 255) / 256), 256, 0, stream>>>(Wih0, Whh0, bih0, bhh0, w0, bias0, IN0);
  k_split_w<<<(int)((2048L * K1 + 255) / 256), 256, 0, stream>>>(Wih1, Whh1, bih1, bhh1, w1, bias1, HID);
  k_lstm<<<NWG, NTHR, LDS_DYN, stream>>>(x16, w0, bias0, w1, bias1,
                                         in1, fcw, fcb, (float*)d_out, bar);
}

// Round 16
// 4328.598 us; speedup vs baseline: 1.2306x; 1.0521x over previous
//
#include <hip/hip_runtime.h>
#include <math.h>

#define T_SEQ 512
#define BATCH 256
#define HID   512
#define IN0   64
#define K1    1024           /* L1: 512 h0 + 512 h1 */
#define K0    576            /* L0: 64 x + 512 h0   */
#define NWG   256
#define NTHR  256
#define LDS_DYN 131072

typedef _Float16 f16x8 __attribute__((ext_vector_type(8)));
typedef float    f32x4 __attribute__((ext_vector_type(4)));

__device__ __forceinline__ float sigm(float x)   { return 1.0f / (1.0f + __expf(-x)); }
__device__ __forceinline__ float tanh_f(float x) { return 2.0f / (1.0f + __expf(-2.0f * x)) - 1.0f; }

__device__ __forceinline__ f32x4 mfma16(f16x8 a, f16x8 b, f32x4 c) {
  return __builtin_amdgcn_mfma_f32_16x16x32_f16(a, b, c, 0, 0, 0);
}

// ---- coherence-point (IF$) bypass ops: nothing is ever cached stale ----
__device__ __forceinline__ f16x8 load_f16x8_cc(const _Float16* p) {
  f16x8 r;
  asm volatile("global_load_dwordx4 %0, %1, off sc0 sc1"
               : "=v"(r) : "v"((const void*)p));
  return r;
}
__device__ __forceinline__ void store_short_wt(const _Float16* p, unsigned v) {
  asm volatile("global_store_short %0, %1, off sc0 sc1"
               :: "v"((const void*)p), "v"(v) : "memory");
}
__device__ __forceinline__ void store_dword_wt(const unsigned* p, unsigned v) {
  asm volatile("global_store_dword %0, %1, off sc0 sc1"
               :: "v"((const void*)p), "v"(v) : "memory");
}

// ---------- prep: W -> fp16, rows permuted r = hcol*4 + gate, k-concat ih|hh ----------
// out layout: [slice s=r>>4][kc=k>>3][row16=r&15][ke=k&7]  (16-B chunks contiguous)
__global__ void k_split_w(const float* __restrict__ Wih, const float* __restrict__ Whh,
                          const float* __restrict__ bih, const float* __restrict__ bhh,
                          _Float16* __restrict__ whi, float* __restrict__ bias, int Kin) {
  int K = Kin + HID;
  long idx = (long)blockIdx.x * 256 + threadIdx.x;
  long total = 2048L * K;
  if (idx < total) {
    int k = (int)(idx % K);
    int r = (int)(idx / K);
    int gate = r & 3, hcol = r >> 2;
    int row = gate * HID + hcol;
    float v = (k < Kin) ? Wih[(long)row * Kin + k] : Whh[(long)row * HID + (k - Kin)];
    long o = (long)(r >> 4) * 16 * K + (long)(k >> 3) * 128 + (r & 15) * 8 + (k & 7);
    whi[o] = (_Float16)v;
  }
  if (idx < 2048) {
    int r = (int)idx;
    int gate = r & 3, hcol = r >> 2;
    int row = gate * HID + hcol;
    bias[r] = bih[row] + bhh[row];
  }
}

// ---------- prep: x[B][T][I] -> fp16 [T][B][I] ----------
__global__ void k_split_x(const float* __restrict__ x, _Float16* __restrict__ x16) {
  int idx = blockIdx.x * 256 + threadIdx.x;   // dst index, [t][b][i]
  int i = idx & 63;
  int b = (idx >> 6) & 255;
  int t = idx >> 14;
  x16[idx] = (_Float16)x[((size_t)b * T_SEQ + t) * IN0 + i];
}

// ---------- per-domain barrier (4 independent batch-group domains), NO fence ----------
// Domain d = wg&3 owns batch rows d*64..d*64+63. All recurrent dataflow
// (h0 self-recurrence, h0->L1, h1 self-recurrence) is batch-diagonal, so a wg
// only depends on the 64 wgs (32 L0 + 32 L1) of its own domain.
// bar[d*32]       : domain arrival counter (monotonic; epoch e done at 64*e)
// bar[256+d*32]   : domain release line (WT store of epoch; polled)
// Data release: callers drain WT stores (s_waitcnt vmcnt(0)) before arriving.
// Data acquire: all cross-wg data (in1) is read via sc0sc1 bypass loads ->
// no stale copy can exist in any L1/L2 -> no per-iteration buffer_inv needed.
__device__ __forceinline__ void grid_barrier(unsigned* bar, unsigned epoch, unsigned dom) {
  __syncthreads();
  if (threadIdx.x == 0) {
    unsigned a = __hip_atomic_fetch_add(&bar[dom * 32], 1u,
                                        __ATOMIC_RELAXED, __HIP_MEMORY_SCOPE_AGENT);
    if (a == epoch * 64u - 1u)     // last of this domain's 64 arrivals this epoch
      store_dword_wt(&bar[256 + dom * 32], epoch);
    while ((int)(__hip_atomic_load(&bar[256 + dom * 32],
                                   __ATOMIC_RELAXED, __HIP_MEMORY_SCOPE_AGENT) - epoch) < 0)
      __builtin_amdgcn_s_sleep(4);
  }
  __syncthreads();
}

// ---------- persistent MFMA LSTM (fp16, 64-row tiles, fence-free, domain sync) ----------
// 256 wgs x 256 thr (4 waves, 1/SIMD). wg<128: layer1, rg=(wg&127)>>2, bg=wg&3;
// wg>=128: layer0 same on (wg-128). wg tile = 64 rows x 64 batch. Domain = bg.
// Wave wv: batch block bg*64+wv*16 (EXCLUSIVE 16-col B tile -> B issued once per
// byte per CU); computes all 4 row-slices: acc[4], c[4].
// fp16 weights for the wg's 64 rows in 128 KB dynamic LDS, loaded ONCE.
// Inner-loop h/x loads are sc0sc1 bypass (asm) with counted vmcnt waits
// (vmcnt(16) -> first half, vmcnt(0) -> rest) + sched_barrier(0) after each
// wait (asm loads are invisible to compiler vmcnt tracking — rule #18).
// D layout: col=lane&15 (batch), row=(lane>>4)*4+reg. Rows permuted hcol*4+gate =>
// lane's 4 acc regs = i,f,g,o of one (hcol,batch): cell update lane-local, c in regs.
// Activations in1 (fp16) [2][256][1024]: cols 0..511 = h0, 512..1023 = h1, k-major.
__global__ __launch_bounds__(NTHR, 1) void k_lstm(
    const _Float16* __restrict__ x16,
    const _Float16* __restrict__ w0, const float* __restrict__ bias0,
    const _Float16* __restrict__ w1, const float* __restrict__ bias1,
    _Float16* __restrict__ in1,
    const float* __restrict__ fcw, const float* __restrict__ fcb,
    float* __restrict__ out, unsigned* __restrict__ bar)
{
  extern __shared__ __align__(16) _Float16 ldsA[];   // 64 rows x KW fp16

  const int tid  = threadIdx.x;
  const int lane = tid & 63;
  const int wv   = __builtin_amdgcn_readfirstlane(tid >> 6);   // 0..3
  const int wg   = blockIdx.x;
  const int layer1 = (wg < 128) ? 1 : 0;
  const int lw   = wg & 127;
  const int rg   = lw >> 2;            // 0..31 row-group (64 rows)
  const int bg   = lw & 3;             // 0..3 batch-group (64 batch) == sync domain
  const unsigned dom = (unsigned)bg;
  const int bbase = bg * 64 + wv * 16;
  const int lr = lane & 15;            // A-row16 / B-batch / D-col offset
  const int lg = lane >> 4;            // k-subgroup (A/B), row-subgroup (D)
  const int KW = layer1 ? K1 : K0;

  // ---- one-time: load this wg's 64-row weight slice into LDS ----
  {
    const f16x8* gw = reinterpret_cast<const f16x8*>((layer1 ? w1 : w0) + (size_t)rg * 64 * KW);
    f16x8* lw16 = reinterpret_cast<f16x8*>(ldsA);
    const int nch = 8 * KW;            // 64*KW/8 chunks of 16 B
    for (int ch = tid; ch < nch; ch += NTHR) lw16[ch] = gw[ch];
  }
  __syncthreads();

  // lane's hidden columns (4 row-slices) and biases
  const float* bsrc = layer1 ? bias1 : bias0;
  float4 b4[4];
  int hcv[4];
  #pragma unroll
  for (int sl = 0; sl < 4; ++sl) {
    hcv[sl] = rg * 16 + sl * 4 + lg;
    b4[sl] = *reinterpret_cast<const float4*>(bsrc + hcv[sl] * 4);
  }
  const f16x8* A = reinterpret_cast<const f16x8*>(ldsA);   // slice sl at sl*2*KW (f16x8 units)

  float c[4] = {0.f, 0.f, 0.f, 0.f};

  #pragma unroll 1
  for (int n = 0; n <= T_SEQ; ++n) {
    const int pr = (n + 1) & 1;   // read parity
    const int pw = n & 1;         // write parity
    const bool active = layer1 ? (n >= 1) : (n < T_SEQ);
    if (active) {
      f32x4 acc[4];
      #pragma unroll
      for (int sl = 0; sl < 4; ++sl) {
        acc[sl][0]=b4[sl].x; acc[sl][1]=b4[sl].y; acc[sl][2]=b4[sl].z; acc[sl][3]=b4[sl].w;
      }

      const _Float16* Bp = in1 + ((size_t)pr * BATCH + bbase) * K1 + (size_t)lr * K1 + lg * 8;

      if (layer1) {
        // 32 k-chunks, all loads issued as sc-bypass; counted waits split halves
        f16x8 bufA[16], bufB[16];
        #pragma unroll
        for (int kk = 0; kk < 16; ++kk)
          bufA[kk] = load_f16x8_cc(Bp + (size_t)kk * 32);
        #pragma unroll
        for (int kk = 0; kk < 16; ++kk)
          bufB[kk] = load_f16x8_cc(Bp + (size_t)(16 + kk) * 32);
        asm volatile("s_waitcnt vmcnt(16)" ::: "memory");   // bufA complete
        __builtin_amdgcn_sched_barrier(0);
        #pragma unroll
        for (int kk = 0; kk < 16; ++kk) {
          const int ac = (kk * 4 + lg) * 16 + lr;
          #pragma unroll
          for (int sl = 0; sl < 4; ++sl)
            acc[sl] = mfma16(A[(size_t)sl * 2 * K1 + ac], bufA[kk], acc[sl]);
        }
        asm volatile("s_waitcnt vmcnt(0)" ::: "memory");    // bufB complete
        __builtin_amdgcn_sched_barrier(0);
        #pragma unroll
        for (int kk = 0; kk < 16; ++kk) {
          const int ac = ((16 + kk) * 4 + lg) * 16 + lr;
          #pragma unroll
          for (int sl = 0; sl < 4; ++sl)
            acc[sl] = mfma16(A[(size_t)sl * 2 * K1 + ac], bufB[kk], acc[sl]);
        }
      } else {
        // x part (2 chunks) + h0 part (16 chunks); x loads are oldest -> return first
        const _Float16* Xp = x16 + ((size_t)n * BATCH + bbase) * IN0 + (size_t)lr * IN0 + lg * 8;
        f16x8 xb0 = load_f16x8_cc(Xp);
        f16x8 xb1 = load_f16x8_cc(Xp + 32);
        f16x8 bufA[16];
        #pragma unroll
        for (int kk = 0; kk < 16; ++kk)
          bufA[kk] = load_f16x8_cc(Bp + (size_t)kk * 32);
        asm volatile("s_waitcnt vmcnt(16)" ::: "memory");   // xb0, xb1 complete
        __builtin_amdgcn_sched_barrier(0);
        #pragma unroll
        for (int sl = 0; sl < 4; ++sl)
          acc[sl] = mfma16(A[(size_t)sl * 2 * K0 + (lg * 16 + lr)], xb0, acc[sl]);
        #pragma unroll
        for (int sl = 0; sl < 4; ++sl)
          acc[sl] = mfma16(A[(size_t)sl * 2 * K0 + ((4 + lg) * 16 + lr)], xb1, acc[sl]);
        asm volatile("s_waitcnt vmcnt(0)" ::: "memory");    // bufA complete
        __builtin_amdgcn_sched_barrier(0);
        #pragma unroll
        for (int kk = 0; kk < 16; ++kk) {
          const int ac = (8 + kk * 4 + lg) * 16 + lr;   // weight k-offset 64
          #pragma unroll
          for (int sl = 0; sl < 4; ++sl)
            acc[sl] = mfma16(A[(size_t)sl * 2 * K0 + ac], bufA[kk], acc[sl]);
        }
      }

      // ---- lane-local cell update; write-through fp16 h stores ----
      const int b = bbase + lr;
      #pragma unroll
      for (int sl = 0; sl < 4; ++sl) {
        float i_ = sigm(acc[sl][0]);
        float f_ = sigm(acc[sl][1]);
        float g_ = tanh_f(acc[sl][2]);
        float o_ = sigm(acc[sl][3]);
        c[sl] = fmaf(f_, c[sl], i_ * g_);
        float hv = o_ * tanh_f(c[sl]);
        _Float16 h16 = (_Float16)hv;
        const int col = (layer1 ? 512 : 0) + hcv[sl];
        const size_t idx = ((size_t)pw * BATCH + b) * K1 + col;
        store_short_wt(in1 + idx, (unsigned)__builtin_bit_cast(unsigned short, h16));
      }
      asm volatile("s_waitcnt vmcnt(0)" ::: "memory");  // release: stores at coherence point
    }
    grid_barrier(bar, (unsigned)(n + 1), dom);
  }

  // ---- final FC on h1[511] (parity 0), cols 512..1023 — wait on ALL domains ----
  if (wg == 0) {
    if (tid == 0) {
      #pragma unroll
      for (int d = 0; d < 4; ++d)
        while ((int)(__hip_atomic_load(&bar[256 + d * 32],
                                       __ATOMIC_RELAXED, __HIP_MEMORY_SCOPE_AGENT)
                     - (unsigned)(T_SEQ + 1)) < 0)
          __builtin_amdgcn_s_sleep(4);
      __builtin_amdgcn_fence(__ATOMIC_ACQUIRE, "agent");   // one-time acquire
    }
    __syncthreads();
    if (tid < BATCH) {
      const _Float16* r = in1 + (size_t)tid * K1 + 512;
      float acc = 0.f;
      #pragma unroll 8
      for (int k = 0; k < HID; ++k)
        acc = fmaf((float)r[k], fcw[k], acc);
      out[tid] = acc + fcb[0];
    }
  }
}

// ---------- host ----------
extern "C" void kernel_launch(void* const* d_in, const int* in_sizes, int n_in,
                              void* d_out, int out_size, void* d_ws, size_t ws_size,
                              hipStream_t stream) {
  const float* x    = (const float*)d_in[0];
  const float* Wih0 = (const float*)d_in[1];
  const float* Whh0 = (const float*)d_in[2];
  const float* bih0 = (const float*)d_in[3];
  const float* bhh0 = (const float*)d_in[4];
  const float* Wih1 = (const float*)d_in[5];
  const float* Whh1 = (const float*)d_in[6];
  const float* bih1 = (const float*)d_in[7];
  const float* bhh1 = (const float*)d_in[8];
  const float* fcw  = (const float*)d_in[9];
  const float* fcb  = (const float*)d_in[10];

  char* ws = (char*)d_ws;
  size_t off = 0;
  auto alloc = [&](size_t bytes) -> char* {
    char* pp = ws + off;
    off = (off + bytes + 1023) & ~(size_t)1023;
    return pp;
  };
  unsigned*  bar  = (unsigned*)alloc(4096);
  _Float16* x16  = (_Float16*)alloc((size_t)T_SEQ * BATCH * IN0 * 2);   // 16.8 MB
  _Float16* w0   = (_Float16*)alloc((size_t)2048 * K0 * 2);             // 2.36 MB
  _Float16* w1   = (_Float16*)alloc((size_t)2048 * K1 * 2);             // 4.2 MB
  float*    bias0 = (float*)alloc(2048 * 4);
  float*    bias1 = (float*)alloc(2048 * 4);
  _Float16* in1  = (_Float16*)alloc((size_t)2 * BATCH * K1 * 2);        // 1 MB

  (void)hipFuncSetAttribute(reinterpret_cast<const void*>(k_lstm),
                            hipFuncAttributeMaxDynamicSharedMemorySize, LDS_DYN);

  (void)hipMemsetAsync(bar, 0, 4096, stream);
  (void)hipMemsetAsync(in1, 0, (size_t)2 * BATCH * K1 * 2, stream);
  k_split_x<<<(T_SEQ * BATCH * IN0) / 256, 256, 0, stream>>>(x, x16);
  k_split_w<<<(int)((2048L * K0 + 255) / 256), 256, 0, stream>>>(Wih0, Whh0, bih0, bhh0, w0, bias0, IN0);
  k_split_w<<<(int)((2048L * K1 + 255) / 256), 256, 0, stream>>>(Wih1, Whh1, bih1, bhh1, w1, bias1, HID);
  k_lstm<<<NWG, NTHR, LDS_DYN, stream>>>(x16, w0, bias0, w1, bias1,
                                         in1, fcw, fcb, (float*)d_out, bar);
}